// Round 6
// baseline (23.178 us; speedup 1.0000x reference)
//
#include <hip/hip_runtime.h>
#include <math.h>

typedef float v2f __attribute__((ext_vector_type(2)));
typedef int   v2i __attribute__((ext_vector_type(2)));

// Problem constants (match reference)
constexpr int B_ = 8;
constexpr int N_ = 128;
constexpr int H_ = 256;
constexpr int W_ = 256;
constexpr int PIX = H_ * W_;                 // 65536 pixels per batch
constexpr int BLOCK = 512;                   // 4 groups x 128 threads
constexpr int GROUPS = 4;                    // N-split: each group does 32 vortices
constexpr int GT = 128;                      // threads per group
constexpr int NPG = N_ / GROUPS;             // 32 vortices per group
constexpr int PPT = 4;                       // pixels per thread
constexpr int PIX_PER_BLOCK = GT * PPT;      // 512
constexpr int BPB = PIX / PIX_PER_BLOCK;     // 128 blocks per batch

// Software exp2 on a packed float pair. Input x <= 0 (product of sq>=0 and a<0).
// Bit trick: t = x + 1.5*2^23 puts round(x) in t's low mantissa bits;
// (as_int(t) << 23) == round(x) << 23 exactly (0x4B400000<<23 wraps to 0).
// Degree-4 poly (Cephes exp2f truncated) for 2^f on f in [-0.5, 0.5],
// rel err ~6e-5 -- far inside the 921.6 absmax budget.
__device__ __forceinline__ v2f fast_exp2(v2f x) {
    x = __builtin_elementwise_max(x, (v2f){-125.0f, -125.0f});  // no exp-wrap
    const float MAGIC = 12582912.0f;  // 1.5 * 2^23
    const v2f t  = x + MAGIC;         // round-to-nearest-int trick
    const v2f nf = t - MAGIC;         // nf = round(x) as float
    const v2f f  = x - nf;            // f in [-0.5, 0.5]
    v2f p = 0.0096181291f;
    p = p * f + 0.0555041087f;
    p = p * f + 0.2402264791f;
    p = p * f + 0.6931471806f;
    p = p * f + 1.0f;                 // p ~= 2^f
    const v2i ti = __builtin_bit_cast(v2i, t);
    const v2i pi = __builtin_bit_cast(v2i, p);
    const v2i ei = pi + (ti << 23);   // inject 2^n into exponent
    return __builtin_bit_cast(v2f, ei);
}

__global__ __launch_bounds__(BLOCK, 4) void gaussian_vorticity_kernel(
    const float* __restrict__ vf,   // [B, N, 4] = (y, x, tau, sigma)
    const float* __restrict__ pts,  // [B, H, W, 2]
    float* __restrict__ out)        // [B, H, W, 1]
{
    __shared__ float4 sv[N_];              // (y, x, a=-log2e/sig2, c=tau/(pi*sig2))
    __shared__ float4 partials[GROUPS - 1][GT];

    const int b = blockIdx.x / BPB;
    const int blkPix = (blockIdx.x % BPB) * PIX_PER_BLOCK;
    const int t = threadIdx.x;
    const int g = t >> 7;                  // group 0..3 -> vortices [32g, 32g+32)
    const int tl = t & (GT - 1);

    // Stage transformed vortex params into LDS (first 128 threads)
    if (t < N_) {
        const float4 v = reinterpret_cast<const float4*>(vf)[b * N_ + t];
        const float inv_sig2 = 1.0f / (v.w * v.w);
        sv[t] = make_float4(v.x, v.y,
                            -1.4426950408889634f * inv_sig2,        // a
                            v.z * 0.3183098861837907f * inv_sig2);  // c
    }
    __syncthreads();

    // 4 pixels per thread; float4 = 2 (y,x) points
    const float4* pbase = reinterpret_cast<const float4*>(
        pts + (size_t)b * PIX * 2) + (blkPix >> 1);
    const float4 p01 = pbase[tl];          // pixels 2tl, 2tl+1
    const float4 p23 = pbase[tl + GT];     // pixels 256+2tl, 256+2tl+1

    // Repack for 2-wide packed fp32
    const v2f py01 = {p01.x, p01.z}, px01 = {p01.y, p01.w};
    const v2f py23 = {p23.x, p23.z}, px23 = {p23.y, p23.w};

    const float4* svg = sv + (g << 5);     // this group's 32 vortices

    v2f acc01 = {0.0f, 0.0f}, acc23 = {0.0f, 0.0f};
#pragma unroll 4
    for (int n = 0; n < NPG; ++n) {
        const float4 v = svg[n];           // broadcast ds_read_b128
        {
            v2f dy = py01 - v.x;
            v2f dx = px01 - v.y;
            v2f sq = dy * dy;
            sq += dx * dx;
            acc01 += fast_exp2(sq * v.z) * v.w;
        }
        {
            v2f dy = py23 - v.x;
            v2f dx = px23 - v.y;
            v2f sq = dy * dy;
            sq += dx * dx;
            acc23 += fast_exp2(sq * v.z) * v.w;
        }
    }

    // Combine the 4 vortex-group partials via LDS
    if (g != 0) {
        partials[g - 1][tl] = make_float4(acc01.x, acc01.y, acc23.x, acc23.y);
    }
    __syncthreads();
    if (g == 0) {
#pragma unroll
        for (int k = 0; k < GROUPS - 1; ++k) {
            const float4 pr = partials[k][tl];
            acc01.x += pr.x; acc01.y += pr.y;
            acc23.x += pr.z; acc23.y += pr.w;
        }
        float2* ob = reinterpret_cast<float2*>(out + (size_t)b * PIX + blkPix);
        ob[tl]      = make_float2(acc01.x, acc01.y);
        ob[tl + GT] = make_float2(acc23.x, acc23.y);
    }
}

extern "C" void kernel_launch(void* const* d_in, const int* in_sizes, int n_in,
                              void* d_out, int out_size, void* d_ws, size_t ws_size,
                              hipStream_t stream) {
    const float* vf  = (const float*)d_in[0];   // [B, N, 4]
    const float* pts = (const float*)d_in[1];   // [B, H, W, 2]
    float* out = (float*)d_out;                 // [B, H, W, 1]

    const int grid = B_ * BPB;                  // 1024 blocks
    gaussian_vorticity_kernel<<<grid, BLOCK, 0, stream>>>(vf, pts, out);
}